// Round 1
// baseline (35.069 us; speedup 1.0000x reference)
//
#include <hip/hip_runtime.h>

// Problem constants (fixed by the bench: B=8, L=512, T=4096, D=512).
constexpr int B = 8;
constexpr int L = 512;
constexpr int D = 512;
constexpr int T = 4096;
constexpr int TILE = 128;                 // t-columns handled per block

constexpr int OUT_REP = B * D * T;        // offset of repeats in d_out
constexpr int OUT_LAT = OUT_REP + B * L;  // offset of latent_lengths

__global__ __launch_bounds__(256) void encoder_expand_kernel(
    const float* __restrict__ enc,   // (B, D, L)
    const float* __restrict__ dur,   // (B, L)
    float* __restrict__ out)         // [expanded (B,D,T) | repeats (B,L) | latent (B)]
{
    const int nchunks = T / TILE;           // 32
    const int b     = blockIdx.x / nchunks;
    const int chunk = blockIdx.x % nchunks;
    const int tid   = threadIdx.x;
    const int lane  = tid & 63;
    const int wave  = tid >> 6;             // 0..3

    __shared__ int cums[L + 1];
    __shared__ int l_of_t[TILE];
    __shared__ int wave_tot[4];

    // ---- repeats + inclusive scan over L=512 (2 elems/thread) ----
    const float* durb = dur + b * L;
    const int l0 = tid * 2;
    int r0 = (int)floorf(durb[l0]     + 0.5f);
    int r1 = (int)floorf(durb[l0 + 1] + 0.5f);
    int pair = r0 + r1;

    int scan = pair;                        // wave-level inclusive scan of pair sums
    #pragma unroll
    for (int off = 1; off < 64; off <<= 1) {
        int n = __shfl_up(scan, off, 64);
        if (lane >= off) scan += n;
    }
    if (lane == 63) wave_tot[wave] = scan;
    __syncthreads();

    int wpre = 0;
    #pragma unroll
    for (int w = 0; w < 4; ++w) wpre += (w < wave) ? wave_tot[w] : 0;
    const int excl = wpre + scan - pair;    // exclusive prefix of this thread's pair

    cums[l0 + 1] = excl + r0;
    cums[l0 + 2] = excl + r0 + r1;
    if (tid == 0) cums[0] = 0;
    __syncthreads();

    const int total = cums[L];

    // ---- side outputs (one chunk per batch does it) ----
    if (chunk == 0) {
        out[OUT_REP + b * L + l0]     = (float)r0;
        out[OUT_REP + b * L + l0 + 1] = (float)r1;
        if (tid == 0) out[OUT_LAT + b] = (float)total;
    }

    // ---- t -> l mapping for this tile (binary search in LDS cums) ----
    const int t0 = chunk * TILE;
    if (tid < TILE) {
        const int t = t0 + tid;
        int lo = 0, hi = L;
        // invariant: cums[lo] <= t (cums[0]=0); find max index with cums[idx] <= t
        while (lo < hi) {
            const int mid = (lo + hi + 1) >> 1;
            if (cums[mid] <= t) lo = mid; else hi = mid - 1;
        }
        l_of_t[tid] = (lo < L) ? lo : -1;   // lo==L  =>  t >= latent_length => 0
    }
    __syncthreads();

    // ---- expansion: thread owns 4 consecutive t, loops over d ----
    const int tg = tid & 31;                // t-group within tile
    const int dl = tid >> 5;                // 0..7
    const int tt = tg * 4;
    const int la = l_of_t[tt];
    const int lb = l_of_t[tt + 1];
    const int lc = l_of_t[tt + 2];
    const int ld = l_of_t[tt + 3];

    const float* encb = enc + (size_t)b * D * L;
    float*       outb = out + (size_t)b * D * T + t0 + tt;

    for (int d = dl; d < D; d += 8) {
        const float* row = encb + (size_t)d * L;   // 2 KB row, L1-resident
        float4 v;
        v.x = (la >= 0) ? row[la] : 0.0f;
        v.y = (lb >= 0) ? row[lb] : 0.0f;
        v.z = (lc >= 0) ? row[lc] : 0.0f;
        v.w = (ld >= 0) ? row[ld] : 0.0f;
        *reinterpret_cast<float4*>(outb + (size_t)d * T) = v;
    }
}

extern "C" void kernel_launch(void* const* d_in, const int* in_sizes, int n_in,
                              void* d_out, int out_size, void* d_ws, size_t ws_size,
                              hipStream_t stream) {
    const float* enc = (const float*)d_in[0];   // (B, D, L) fp32
    const float* dur = (const float*)d_in[1];   // (B, L)    fp32
    float* out = (float*)d_out;
    encoder_expand_kernel<<<dim3(B * (T / TILE)), dim3(256), 0, stream>>>(enc, dur, out);
}

// Round 2
// 20.314 us; speedup vs baseline: 1.7263x; 1.7263x over previous
//
#include <hip/hip_runtime.h>

// Problem constants (fixed by the bench: B=8, L=512, T=4096, D=512).
constexpr int B = 8;
constexpr int L = 512;
constexpr int D = 512;
constexpr int T = 4096;
constexpr int TILE = 128;                 // t-columns handled per block
constexpr int DS   = 8;                   // d-splits per (b,chunk)
constexpr int DROWS = D / DS;             // 64 d-rows per block

constexpr int OUT_REP = B * D * T;        // offset of repeats in d_out
constexpr int OUT_LAT = OUT_REP + B * L;  // offset of latent_lengths

__global__ __launch_bounds__(256) void encoder_expand_kernel(
    const float* __restrict__ enc,   // (B, D, L)
    const float* __restrict__ dur,   // (B, L)
    float* __restrict__ out)         // [expanded (B,D,T) | repeats (B,L) | latent (B)]
{
    const int b     = blockIdx.y;
    const int chunk = blockIdx.x / DS;      // 0..31
    const int ds    = blockIdx.x % DS;      // 0..7
    const int tid   = threadIdx.x;
    const int lane  = tid & 63;
    const int wave  = tid >> 6;             // 0..3

    __shared__ int cums[L + 1];
    __shared__ int l_of_t[TILE];
    __shared__ int wave_tot[4];

    // ---- repeats + inclusive scan over L=512 (2 elems/thread) ----
    const float* durb = dur + b * L;
    const int l0 = tid * 2;
    int r0 = (int)floorf(durb[l0]     + 0.5f);
    int r1 = (int)floorf(durb[l0 + 1] + 0.5f);
    int pair = r0 + r1;

    int scan = pair;                        // wave-level inclusive scan of pair sums
    #pragma unroll
    for (int off = 1; off < 64; off <<= 1) {
        int n = __shfl_up(scan, off, 64);
        if (lane >= off) scan += n;
    }
    if (lane == 63) wave_tot[wave] = scan;
    __syncthreads();

    int wpre = 0;
    #pragma unroll
    for (int w = 0; w < 4; ++w) wpre += (w < wave) ? wave_tot[w] : 0;
    const int excl = wpre + scan - pair;    // exclusive prefix of this thread's pair

    cums[l0 + 1] = excl + r0;
    cums[l0 + 2] = excl + r0 + r1;
    if (tid == 0) cums[0] = 0;
    __syncthreads();

    const int total = cums[L];

    // ---- side outputs (one block per batch does it) ----
    if (chunk == 0 && ds == 0) {
        out[OUT_REP + b * L + l0]     = (float)r0;
        out[OUT_REP + b * L + l0 + 1] = (float)r1;
        if (tid == 0) out[OUT_LAT + b] = (float)total;
    }

    // ---- t -> l mapping for this tile (binary search in LDS cums) ----
    const int t0 = chunk * TILE;
    if (tid < TILE) {
        const int t = t0 + tid;
        int lo = 0, hi = L;
        // invariant: cums[lo] <= t (cums[0]=0); find max index with cums[idx] <= t
        while (lo < hi) {
            const int mid = (lo + hi + 1) >> 1;
            if (cums[mid] <= t) lo = mid; else hi = mid - 1;
        }
        l_of_t[tid] = (lo < L) ? lo : -1;   // lo==L  =>  t >= latent_length => 0
    }
    __syncthreads();

    // ---- expansion: thread owns 4 consecutive t, loops over its d slice ----
    const int tg = tid & 31;                // t-group within tile
    const int dl = tid >> 5;                // 0..7
    const int tt = tg * 4;
    const int la = l_of_t[tt];
    const int lb = l_of_t[tt + 1];
    const int lc = l_of_t[tt + 2];
    const int ld = l_of_t[tt + 3];

    const int d0 = ds * DROWS;
    const float* encb = enc + (size_t)b * D * L + (size_t)d0 * L;
    float*       outb = out + (size_t)b * D * T + (size_t)d0 * T + t0 + tt;

    #pragma unroll
    for (int d = dl; d < DROWS; d += 8) {
        const float* row = encb + (size_t)d * L;   // 2 KB row, L1/L2-resident
        float4 v;
        v.x = (la >= 0) ? row[la] : 0.0f;
        v.y = (lb >= 0) ? row[lb] : 0.0f;
        v.z = (lc >= 0) ? row[lc] : 0.0f;
        v.w = (ld >= 0) ? row[ld] : 0.0f;
        *reinterpret_cast<float4*>(outb + (size_t)d * T) = v;
    }
}

extern "C" void kernel_launch(void* const* d_in, const int* in_sizes, int n_in,
                              void* d_out, int out_size, void* d_ws, size_t ws_size,
                              hipStream_t stream) {
    const float* enc = (const float*)d_in[0];   // (B, D, L) fp32
    const float* dur = (const float*)d_in[1];   // (B, L)    fp32
    float* out = (float*)d_out;
    encoder_expand_kernel<<<dim3((T / TILE) * DS, B), dim3(256), 0, stream>>>(enc, dur, out);
}

// Round 3
// 20.276 us; speedup vs baseline: 1.7296x; 1.0019x over previous
//
#include <hip/hip_runtime.h>

// Problem constants (fixed by the bench: B=8, L=512, T=4096, D=512).
constexpr int B = 8;
constexpr int L = 512;
constexpr int D = 512;
constexpr int T = 4096;
constexpr int TILE  = 256;                // t-columns handled per block
constexpr int DS    = 16;                 // d-splits per (b,chunk)
constexpr int DROWS = D / DS;             // 32 d-rows per block

constexpr int OUT_REP = B * D * T;        // offset of repeats in d_out
constexpr int OUT_LAT = OUT_REP + B * L;  // offset of latent_lengths

__global__ __launch_bounds__(256) void encoder_expand_kernel(
    const float* __restrict__ enc,   // (B, D, L)
    const float* __restrict__ dur,   // (B, L)
    float* __restrict__ out)         // [expanded (B,D,T) | repeats (B,L) | latent (B)]
{
    const int b     = blockIdx.y;
    const int chunk = blockIdx.x / DS;      // 0..T/TILE-1
    const int ds    = blockIdx.x % DS;      // 0..DS-1
    const int tid   = threadIdx.x;
    const int lane  = tid & 63;
    const int wave  = tid >> 6;             // 0..3

    __shared__ int cums[L + 1];
    __shared__ int l_of_t[TILE];
    __shared__ int wave_tot[4];

    // ---- repeats + inclusive scan over L=512 (2 elems/thread) ----
    const float* durb = dur + b * L;
    const int l0 = tid * 2;
    int r0 = (int)floorf(durb[l0]     + 0.5f);
    int r1 = (int)floorf(durb[l0 + 1] + 0.5f);
    int pair = r0 + r1;

    int scan = pair;                        // wave-level inclusive scan of pair sums
    #pragma unroll
    for (int off = 1; off < 64; off <<= 1) {
        int n = __shfl_up(scan, off, 64);
        if (lane >= off) scan += n;
    }
    if (lane == 63) wave_tot[wave] = scan;
    __syncthreads();

    int wpre = 0;
    #pragma unroll
    for (int w = 0; w < 4; ++w) wpre += (w < wave) ? wave_tot[w] : 0;
    const int excl = wpre + scan - pair;    // exclusive prefix of this thread's pair

    cums[l0 + 1] = excl + r0;
    cums[l0 + 2] = excl + r0 + r1;
    if (tid == 0) cums[0] = 0;
    __syncthreads();

    const int total = cums[L];

    // ---- side outputs (one block per batch does it) ----
    if (chunk == 0 && ds == 0) {
        out[OUT_REP + b * L + l0]     = (float)r0;
        out[OUT_REP + b * L + l0 + 1] = (float)r1;
        if (tid == 0) out[OUT_LAT + b] = (float)total;
    }

    // ---- t -> l mapping for this tile (binary search in LDS cums) ----
    const int t0 = chunk * TILE;
    {
        const int t = t0 + tid;
        int lo = 0, hi = L;
        // invariant: cums[lo] <= t (cums[0]=0); find max index with cums[idx] <= t
        while (lo < hi) {
            const int mid = (lo + hi + 1) >> 1;
            if (cums[mid] <= t) lo = mid; else hi = mid - 1;
        }
        l_of_t[tid] = (lo < L) ? lo : -1;   // lo==L  =>  t >= latent_length => 0
    }
    __syncthreads();

    // ---- expansion: thread owns 4 consecutive t, covers DROWS d-rows ----
    // Wave layout: all 64 lanes of a wave share the same d-row per store
    // instruction -> one fully contiguous 1 KB segment per global_store_dwordx4.
    const int tg = tid & 63;                // t-group within tile (64 groups of 4)
    const int dl = tid >> 6;                // 0..3 d-lane
    const int tt = tg * 4;
    const int la = l_of_t[tt];
    const int lb = l_of_t[tt + 1];
    const int lc = l_of_t[tt + 2];
    const int ld = l_of_t[tt + 3];

    const int d0 = ds * DROWS;
    const float* encb = enc + (size_t)b * D * L + (size_t)d0 * L;
    float*       outb = out + (size_t)b * D * T + (size_t)d0 * T + t0 + tt;

    if (la < 0) {
        // whole 4-t group is past latent_length: pure zero stream, no loads
        const float4 z = make_float4(0.f, 0.f, 0.f, 0.f);
        #pragma unroll
        for (int j = 0; j < DROWS / 4; ++j)
            *reinterpret_cast<float4*>(outb + (size_t)(dl + j * 4) * T) = z;
    } else {
        const int lbx = (lb < 0) ? 0 : lb;
        const int lcx = (lc < 0) ? 0 : lc;
        const int ldx = (ld < 0) ? 0 : ld;
        const bool mb = (lb >= 0), mc = (lc >= 0), md = (ld >= 0);

        // two prefetch groups of 4 rows: 16 loads in flight before first store
        #pragma unroll
        for (int g = 0; g < 2; ++g) {
            float4 v[4];
            #pragma unroll
            for (int i = 0; i < 4; ++i) {
                const float* row = encb + (size_t)(dl + (g * 4 + i) * 4) * L;
                v[i].x = row[la];
                v[i].y = row[lbx];
                v[i].z = row[lcx];
                v[i].w = row[ldx];
            }
            #pragma unroll
            for (int i = 0; i < 4; ++i) {
                float4 w = v[i];
                if (!mb) w.y = 0.f;
                if (!mc) w.z = 0.f;
                if (!md) w.w = 0.f;
                *reinterpret_cast<float4*>(outb + (size_t)(dl + (g * 4 + i) * 4) * T) = w;
            }
        }
    }
}

extern "C" void kernel_launch(void* const* d_in, const int* in_sizes, int n_in,
                              void* d_out, int out_size, void* d_ws, size_t ws_size,
                              hipStream_t stream) {
    const float* enc = (const float*)d_in[0];   // (B, D, L) fp32
    const float* dur = (const float*)d_in[1];   // (B, L)    fp32
    float* out = (float*)d_out;
    encoder_expand_kernel<<<dim3((T / TILE) * DS, B), dim3(256), 0, stream>>>(enc, dur, out);
}